// Round 12
// baseline (249.292 us; speedup 1.0000x reference)
//
#include <hip/hip_runtime.h>
#include <math.h>

// Problem constants (fixed by reference)
#define BB 4
#define LL 1024
#define HH 16
#define DH 64
#define DM 1024
#define MM (BB * LL)   // 4096 rows for the projections

typedef short bf16x8 __attribute__((ext_vector_type(8)));
typedef float f32x4  __attribute__((ext_vector_type(4)));
typedef unsigned short u16x4 __attribute__((ext_vector_type(4)));
typedef unsigned short u16x8 __attribute__((ext_vector_type(8)));
typedef unsigned int   u32x2 __attribute__((ext_vector_type(2)));

__device__ __forceinline__ unsigned short f2bf(float x) {
    union { float f; unsigned u; } v; v.f = x;
    unsigned r = v.u + 0x7fff + ((v.u >> 16) & 1);   // round-to-nearest-even
    return (unsigned short)(r >> 16);
}

__device__ __forceinline__ unsigned int fbits(float x) {
    union { float f; unsigned u; } v; v.f = x; return v.u;
}

// async global->LDS, 16B per lane; LDS dest = wave-uniform base + lane*16
__device__ __forceinline__ void gl2lds16(const unsigned short* g, unsigned short* l) {
    __builtin_amdgcn_global_load_lds(
        (const __attribute__((address_space(1))) unsigned int*)g,
        (__attribute__((address_space(3))) unsigned int*)l, 16, 0, 0);
}

// XCD-aware tile mapping for 128x64 tiles (32 M-tiles x 16 N-tiles = 512):
// blocks sharing an A-strip (same tM) have ids congruent mod 8 -> same XCD.
__device__ __forceinline__ void tile_map64(int n, int& tM, int& tN) {
    tM = ((n >> 7) * 8 + (n & 7)) * 128;
    tN = ((n >> 3) & 15) * 64;
}

// ---------------------------------------------------------------------------
// Prep kernel (weights + rope table only; input cvt now fused into gemm_qkv):
//  z 0..3 : W[K,N] f32 -> Wt[N,K] bf16 transpose, 32x32 tiles (1024 blocks)
//  z == 4 : rope cos/sin table (1024 l x 32 d) — first 128 blocks only
// ---------------------------------------------------------------------------
__global__ __launch_bounds__(256) void prep_kernel(
    const float* __restrict__ w0, const float* __restrict__ w1,
    const float* __restrict__ w2, const float* __restrict__ w3,
    unsigned short* __restrict__ t0, unsigned short* __restrict__ t1,
    unsigned short* __restrict__ t2, unsigned short* __restrict__ t3,
    float* __restrict__ ct, float* __restrict__ st)
{
    const int z = blockIdx.z;
    const int bid = blockIdx.x, tid = threadIdx.x;

    if (z == 4) {
        int idx = bid * 256 + tid;
        if (idx < LL * 32) {
            int l = idx >> 5, d = idx & 31;
            const float coef = -0.28782313662425583f;   // -ln(10000)/32
            float ang = (float)l * expf((float)d * coef);
            float s, c;
            sincosf(ang, &s, &c);
            ct[idx] = c;
            st[idx] = s;
        }
        return;
    }
    const float* in = (z == 0) ? w0 : (z == 1) ? w1 : (z == 2) ? w2 : w3;
    unsigned short* out = (z == 0) ? t0 : (z == 1) ? t1 : (z == 2) ? t2 : t3;
    __shared__ float tile[32][33];
    int tx = tid & 31, ty = tid >> 5;   // 32 x 8
    int c0 = (bid & 31) * 32, r0 = (bid >> 5) * 32;
    #pragma unroll
    for (int j = 0; j < 32; j += 8)
        tile[ty + j][tx] = in[(size_t)(r0 + ty + j) * 1024 + c0 + tx];
    __syncthreads();
    #pragma unroll
    for (int j = 0; j < 32; j += 8)
        out[(size_t)(c0 + ty + j) * 1024 + r0 + tx] = f2bf(tile[tx][ty + j]);
}

// ---------------------------------------------------------------------------
// QKV projections, fused over blockIdx.z (0=q rope+scale, 1=k rope, 2=v).
// A read DIRECTLY as f32: coalesced float4 loads -> in-register RNE f2bf ->
// ds_write_b128 with the SAME address pattern / XOR swizzle as global_load_lds
// (contiguous 16B/lane => conflict-free). B (pre-transposed bf16 weights)
// stays DMA-staged. grid (512, 1, 3) -> 6 blocks/CU. 128x64 tile, BK=64.
// Q scale = 0.125*log2(e) (attn uses exp2). z==2 writes V^T [bh][d][l] (b64).
// ---------------------------------------------------------------------------
__global__ __launch_bounds__(256) void gemm_qkv_kernel(
    const float* __restrict__ Aq, const float* __restrict__ Ak,
    const float* __restrict__ Av,
    const unsigned short* __restrict__ Wqt, const unsigned short* __restrict__ Wkt,
    const unsigned short* __restrict__ Wvt,
    const float* __restrict__ bq, const float* __restrict__ bk, const float* __restrict__ bv,
    const float* __restrict__ ct, const float* __restrict__ st,
    unsigned short* __restrict__ oq, unsigned short* __restrict__ ok,
    unsigned short* __restrict__ vt)
{
    __shared__ __align__(16) unsigned short As[128 * 64];
    __shared__ __align__(16) unsigned short Bs[64 * 64];

    const int z = blockIdx.z;
    const float* Af          = (z == 0) ? Aq  : (z == 1) ? Ak  : Av;
    const unsigned short* Bt = (z == 0) ? Wqt : (z == 1) ? Wkt : Wvt;
    const float* bias        = (z == 0) ? bq  : (z == 1) ? bk  : bv;

    int tM, tN;
    tile_map64(blockIdx.x, tM, tN);

    const int tid  = threadIdx.x;
    const int wave = tid >> 6, lane = tid & 63;
    const int g = lane >> 4, lm = lane & 15;
    const int wm = wave >> 1, wn = wave & 1;
    const int lr = lane >> 3, lk = lane & 7;
    const int kbl = lk ^ lr;                    // swizzled k-block

    f32x4 acc[4][2] = {};

    for (int kt = 0; kt < 16; ++kt) {
        const int k0 = kt * 64;
        if (kt) __syncthreads();
        // A: 128 rows x 64 k, f32 -> bf16 in-register, b128 LDS writes
        #pragma unroll
        for (int it = 0; it < 4; ++it) {
            int r = wave * 32 + it * 8 + lr;
            const float* src = Af + (size_t)(tM + r) * 1024 + k0 + kbl * 8;
            float4 f0 = *(const float4*)src;
            float4 f1 = *(const float4*)(src + 4);
            u16x8 p;
            p[0] = f2bf(f0.x); p[1] = f2bf(f0.y); p[2] = f2bf(f0.z); p[3] = f2bf(f0.w);
            p[4] = f2bf(f1.x); p[5] = f2bf(f1.y); p[6] = f2bf(f1.z); p[7] = f2bf(f1.w);
            *(u16x8*)&As[r * 64 + lk * 8] = p;
        }
        // B: 64 rows via async DMA
        #pragma unroll
        for (int it = 0; it < 2; ++it) {
            int rbase = wave * 16 + it * 8;
            int r = rbase + lr;
            gl2lds16(Bt + (size_t)(tN + r) * 1024 + k0 + kbl * 8, Bs + rbase * 64);
        }
        __syncthreads();

        #pragma unroll
        for (int kk = 0; kk < 2; ++kk) {
            bf16x8 a[4], b[2];
            const int sw = ((kk * 4 + g) ^ (lm & 7)) * 8;
            #pragma unroll
            for (int mt = 0; mt < 4; ++mt)
                a[mt] = *(const bf16x8*)&As[(wm * 64 + mt * 16 + lm) * 64 + sw];
            #pragma unroll
            for (int nt = 0; nt < 2; ++nt)
                b[nt] = *(const bf16x8*)&Bs[(wn * 16 + nt * 32 + lm) * 64 + sw];
            #pragma unroll
            for (int mt = 0; mt < 4; ++mt)
                #pragma unroll
                for (int nt = 0; nt < 2; ++nt)
                    acc[mt][nt] = __builtin_amdgcn_mfma_f32_16x16x32_bf16(
                        a[mt], b[nt], acc[mt][nt], 0, 0, 0);
        }
    }

    const int h = tN >> 6;                      // this tile's head
    float bvv[2];
    #pragma unroll
    for (int nt = 0; nt < 2; ++nt) bvv[nt] = bias[tN + wn * 16 + nt * 32 + lm];

    if (z == 2) {                               // V: write V^T [bh][d][l], b64
        #pragma unroll
        for (int mt = 0; mt < 4; ++mt) {
            int row0 = tM + wm * 64 + mt * 16 + g * 4;   // 4 consecutive rows
            int b = row0 >> 10, l0 = row0 & 1023;
            #pragma unroll
            for (int nt = 0; nt < 2; ++nt) {
                int dloc = wn * 16 + nt * 32 + lm;
                u16x4 p4;
                #pragma unroll
                for (int r = 0; r < 4; ++r)
                    p4[r] = f2bf(acc[mt][nt][r] + bvv[nt]);
                *(u16x4*)(vt + (((size_t)(b * HH + h) * DH + dloc) << 10) + l0) = p4;
            }
        }
    } else {                                    // Q/K: rope from table
        unsigned short* out = (z == 0) ? oq : ok;
        const float sc = (z == 0) ? 0.125f * 1.4426950408889634f : 1.0f;
        const int dlo = wn * 16 + lm;           // in [0,32): rope pair (dlo, dlo+32)
        #pragma unroll
        for (int mt = 0; mt < 4; ++mt)
            #pragma unroll
            for (int r = 0; r < 4; ++r) {
                int row = tM + wm * 64 + mt * 16 + g * 4 + r;
                int b = row >> 10, l = row & 1023;
                float c = ct[l * 32 + dlo];
                float s = st[l * 32 + dlo];
                unsigned short* orow = out + ((size_t)(b * HH + h) * LL + l) * DH;
                float t1 = acc[mt][0][r] + bvv[0];
                float t2 = acc[mt][1][r] + bvv[1];
                orow[dlo]      = f2bf((t1 * c - t2 * s) * sc);
                orow[dlo + 32] = f2bf((t1 * s + t2 * c) * sc);
            }
    }
}

// ---------------------------------------------------------------------------
// Output projection: f32 C = ctx(bf16).Wot^T + bo. grid (512), bf16 DMA core.
// ---------------------------------------------------------------------------
__global__ __launch_bounds__(256) void gemm_out_kernel(
    const unsigned short* __restrict__ A, const unsigned short* __restrict__ Bt,
    const float* __restrict__ bias, float* __restrict__ C)
{
    __shared__ __align__(16) unsigned short As[128 * 64];
    __shared__ __align__(16) unsigned short Bs[64 * 64];

    int tM, tN;
    tile_map64(blockIdx.x, tM, tN);

    const int tid  = threadIdx.x;
    const int wave = tid >> 6, lane = tid & 63;
    const int g = lane >> 4, lm = lane & 15;
    const int wm = wave >> 1, wn = wave & 1;
    const int lr = lane >> 3, lk = lane & 7;
    const int kbl = lk ^ lr;

    f32x4 acc[4][2] = {};

    for (int kt = 0; kt < 16; ++kt) {
        const int k0 = kt * 64;
        if (kt) __syncthreads();
        #pragma unroll
        for (int it = 0; it < 4; ++it) {        // A: 128 rows
            int rbase = wave * 32 + it * 8;
            int r = rbase + lr;
            gl2lds16(A + (size_t)(tM + r) * 1024 + k0 + kbl * 8, As + rbase * 64);
        }
        #pragma unroll
        for (int it = 0; it < 2; ++it) {        // B: 64 rows
            int rbase = wave * 16 + it * 8;
            int r = rbase + lr;
            gl2lds16(Bt + (size_t)(tN + r) * 1024 + k0 + kbl * 8, Bs + rbase * 64);
        }
        __syncthreads();

        #pragma unroll
        for (int kk = 0; kk < 2; ++kk) {
            bf16x8 a[4], b[2];
            const int sw = ((kk * 4 + g) ^ (lm & 7)) * 8;
            #pragma unroll
            for (int mt = 0; mt < 4; ++mt)
                a[mt] = *(const bf16x8*)&As[(wm * 64 + mt * 16 + lm) * 64 + sw];
            #pragma unroll
            for (int nt = 0; nt < 2; ++nt)
                b[nt] = *(const bf16x8*)&Bs[(wn * 16 + nt * 32 + lm) * 64 + sw];
            #pragma unroll
            for (int mt = 0; mt < 4; ++mt)
                #pragma unroll
                for (int nt = 0; nt < 2; ++nt)
                    acc[mt][nt] = __builtin_amdgcn_mfma_f32_16x16x32_bf16(
                        a[mt], b[nt], acc[mt][nt], 0, 0, 0);
        }
    }

    float bvv[2];
    #pragma unroll
    for (int nt = 0; nt < 2; ++nt) bvv[nt] = bias[tN + wn * 16 + nt * 32 + lm];
    #pragma unroll
    for (int mt = 0; mt < 4; ++mt)
        #pragma unroll
        for (int r = 0; r < 4; ++r) {
            int row = tM + wm * 64 + mt * 16 + g * 4 + r;
            float* crow = C + (size_t)row * DM + tN;
            #pragma unroll
            for (int nt = 0; nt < 2; ++nt)
                crow[wn * 16 + nt * 32 + lm] = acc[mt][nt][r] + bvv[nt];
        }
}

// ---------------------------------------------------------------------------
// Flash-style bf16 MFMA attention, S^T form, 512-thread blocks (8 waves).
// Wave pairs: pair = wave>>1 owns q-strip rows pair*16..+15; half = wave&1
// splits the 64 j-columns (QK^T) and 64 d-outputs (PV). 4 blocks/CU x 8
// waves = 32 waves/CU. P pair-shared (disjoint j-halves), barrier before PV.
// 1-D grid, bh = n&63 so each head's blocks share an XCD (L2 locality).
// ---------------------------------------------------------------------------
#define PSTR 72

__global__ __launch_bounds__(512) void attn_mfma_kernel(
    const unsigned short* __restrict__ q, const unsigned short* __restrict__ k,
    const unsigned short* __restrict__ vt, unsigned short* __restrict__ ctx)
{
    __shared__ __align__(16) unsigned short Ks[64 * 64];
    __shared__ __align__(16) unsigned short Vs[64 * 64];
    __shared__ __align__(16) unsigned short Pb[4][16 * PSTR];
    __shared__ float Sm[4][2][16];

    const int tid  = threadIdx.x;
    const int wave = tid >> 6, lane = tid & 63;
    const int pair = wave >> 1, half = wave & 1;
    const int g = lane >> 4, lm = lane & 15;
    const int lr = lane >> 3, lk = lane & 7;
    const int kbl = lk ^ lr;
    const int n = blockIdx.x;
    const int bh = n & 63;              // XCD-swizzle: bh%8 == n%8 == XCD
    const int qbase = (n >> 6) * 64;

    const unsigned short* qg  = q  + (size_t)(bh * LL + qbase) * DH;
    const unsigned short* kg  = k  + (size_t)bh * LL * DH;
    const unsigned short* vtg = vt + (size_t)bh * DH * LL;   // [64 d][1024 l]

    bf16x8 aq[2];
    {
        const unsigned short* qrow = qg + (pair * 16 + lm) * DH;
        aq[0] = *(const bf16x8*)(qrow + g * 8);
        aq[1] = *(const bf16x8*)(qrow + 32 + g * 8);
    }

    f32x4 acc[2] = {};
    float lsum = 0.f;       // partial row-sum for m=lm over this wave's j-half

    for (int kt = 0; kt < 16; ++kt) {
        if (kt) __syncthreads();
        {   // 8 waves stage 64 K rows + 64 V^T rows in one call each
            int r = wave * 8 + lr;
            gl2lds16(kg  + (size_t)(kt * 64 + r) * DH + kbl * 8, Ks + wave * 8 * 64);
            gl2lds16(vtg + (size_t)r * LL + kt * 64 + kbl * 8,  Vs + wave * 8 * 64);
        }
        __syncthreads();

        // S^T = K . Q^T on this wave's j-half (t-tiles half*2, half*2+1)
        f32x4 s[2] = {};
        #pragma unroll
        for (int kk = 0; kk < 2; ++kk) {
            const int sw = ((kk * 4 + g) ^ (lm & 7)) * 8;
            #pragma unroll
            for (int t = 0; t < 2; ++t) {
                bf16x8 ak = *(const bf16x8*)&Ks[(half * 32 + t * 16 + lm) * 64 + sw];
                s[t] = __builtin_amdgcn_mfma_f32_16x16x32_bf16(ak, aq[kk], s[t], 0, 0, 0);
            }
        }

        // P = exp2(s); truncation-pack via v_perm; partial row sum
        #pragma unroll
        for (int t = 0; t < 2; ++t) {
            float p0 = exp2f(s[t][0]), p1 = exp2f(s[t][1]);
            float p2 = exp2f(s[t][2]), p3 = exp2f(s[t][3]);
            lsum += (p0 + p1) + (p2 + p3);
            u32x2 pk;
            pk[0] = __builtin_amdgcn_perm(fbits(p1), fbits(p0), 0x07060302u);
            pk[1] = __builtin_amdgcn_perm(fbits(p3), fbits(p2), 0x07060302u);
            *(u32x2*)&Pb[pair][lm * PSTR + half * 32 + t * 16 + g * 4] = pk;
        }
        __syncthreads();    // both j-halves of P visible across the pair

        // O += P V on this wave's d-half (dt-tiles half*2, half*2+1)
        #pragma unroll
        for (int kk = 0; kk < 2; ++kk) {
            const int sw = ((kk * 4 + g) ^ (lm & 7)) * 8;
            bf16x8 ap = *(const bf16x8*)&Pb[pair][lm * PSTR + kk * 32 + g * 8];
            #pragma unroll
            for (int dt = 0; dt < 2; ++dt) {
                bf16x8 bv = *(const bf16x8*)&Vs[(half * 32 + dt * 16 + lm) * 64 + sw];
                acc[dt] = __builtin_amdgcn_mfma_f32_16x16x32_bf16(ap, bv, acc[dt], 0, 0, 0);
            }
        }
    }

    // Row sums: reduce over g within wave, then combine halves via LDS
    float ts = lsum;
    ts += __shfl_xor(ts, 16, 64);
    ts += __shfl_xor(ts, 32, 64);
    if (lane < 16) Sm[pair][half][lane] = ts;
    __syncthreads();

    // Epilogue: lane's C rows are m = g*4+r; d = half*32 + dt*16 + lm
    int b = bh >> 4, h = bh & 15;
    #pragma unroll
    for (int r = 0; r < 4; ++r) {
        int m = g * 4 + r;
        float inv = 1.f / (Sm[pair][0][m] + Sm[pair][1][m]);
        int qrow = qbase + pair * 16 + m;
        unsigned short* orow = ctx + (size_t)(b * LL + qrow) * DM + h * DH;
        #pragma unroll
        for (int dt = 0; dt < 2; ++dt)
            orow[half * 32 + dt * 16 + lm] = f2bf(acc[dt][r] * inv);
    }
}

// ---------------------------------------------------------------------------
extern "C" void kernel_launch(void* const* d_in, const int* in_sizes, int n_in,
                              void* d_out, int out_size, void* d_ws, size_t ws_size,
                              hipStream_t stream) {
    const float* queries = (const float*)d_in[0];
    const float* keys    = (const float*)d_in[1];
    const float* values  = (const float*)d_in[2];
    const float* Wq = (const float*)d_in[3];
    const float* bq = (const float*)d_in[4];
    const float* Wk = (const float*)d_in[5];
    const float* bk = (const float*)d_in[6];
    const float* Wv = (const float*)d_in[7];
    const float* bv = (const float*)d_in[8];
    const float* Wo = (const float*)d_in[9];
    const float* bo = (const float*)d_in[10];
    float* out = (float*)d_out;

    // Workspace (bf16 elements), 40 MB. Rope tables (256 KB f32) live at the
    // head of the ctx region: consumed by gemm_qkv BEFORE attn writes ctx.
    unsigned short* Wqt  = (unsigned short*)d_ws;
    unsigned short* Wkt  = Wqt + (size_t)DM * DM;
    unsigned short* Wvt  = Wkt + (size_t)DM * DM;
    unsigned short* Wot  = Wvt + (size_t)DM * DM;
    unsigned short* q_ws = Wot + (size_t)DM * DM;
    unsigned short* k_ws = q_ws + (size_t)MM * DM;
    unsigned short* vt   = k_ws + (size_t)MM * DM;
    unsigned short* ctx  = vt   + (size_t)MM * DM;
    float* rope_cos = (float*)ctx;                 // 32K floats
    float* rope_sin = rope_cos + LL * 32;          // 32K floats

    prep_kernel<<<dim3(1024, 1, 5), 256, 0, stream>>>(
        Wq, Wk, Wv, Wo, Wqt, Wkt, Wvt, Wot, rope_cos, rope_sin);
    gemm_qkv_kernel<<<dim3(512, 1, 3), 256, 0, stream>>>(
        queries, keys, values, Wqt, Wkt, Wvt, bq, bk, bv, rope_cos, rope_sin,
        q_ws, k_ws, vt);
    attn_mfma_kernel<<<dim3(LL / 64 * BB * HH), 512, 0, stream>>>(
        q_ws, k_ws, vt, ctx);
    gemm_out_kernel<<<dim3(512), 256, 0, stream>>>(
        ctx, Wot, bo, out);
}

// Round 13
// 204.708 us; speedup vs baseline: 1.2178x; 1.2178x over previous
//
#include <hip/hip_runtime.h>
#include <math.h>

// Problem constants (fixed by reference)
#define BB 4
#define LL 1024
#define HH 16
#define DH 64
#define DM 1024
#define MM (BB * LL)   // 4096 rows for the projections

typedef short bf16x8 __attribute__((ext_vector_type(8)));
typedef float f32x4  __attribute__((ext_vector_type(4)));
typedef unsigned short u16x4 __attribute__((ext_vector_type(4)));
typedef unsigned int   u32x2 __attribute__((ext_vector_type(2)));

__device__ __forceinline__ unsigned short f2bf(float x) {
    union { float f; unsigned u; } v; v.f = x;
    unsigned r = v.u + 0x7fff + ((v.u >> 16) & 1);   // round-to-nearest-even
    return (unsigned short)(r >> 16);
}

__device__ __forceinline__ unsigned int fbits(float x) {
    union { float f; unsigned u; } v; v.f = x; return v.u;
}

// async global->LDS, 16B per lane; LDS dest = wave-uniform base + lane*16
__device__ __forceinline__ void gl2lds16(const unsigned short* g, unsigned short* l) {
    __builtin_amdgcn_global_load_lds(
        (const __attribute__((address_space(1))) unsigned int*)g,
        (__attribute__((address_space(3))) unsigned int*)l, 16, 0, 0);
}

// XCD-aware tile mapping for 128x64 tiles (32 M-tiles x 16 N-tiles = 512):
// blocks sharing an A-strip (same tM) have ids congruent mod 8 -> same XCD.
__device__ __forceinline__ void tile_map64(int n, int& tM, int& tN) {
    tM = ((n >> 7) * 8 + (n & 7)) * 128;
    tN = ((n >> 3) & 15) * 64;
}

// ---------------------------------------------------------------------------
// Fused prep kernel, grid (1024, 1, 8):
//  z 0..2 : f32 -> bf16 flat convert of queries/keys/values (16 elem/thread)
//  z == 3 : rope cos/sin table (1024 l x 32 d) — first 128 blocks only
//  z 4..7 : W[K,N] f32 -> Wt[N,K] bf16 transpose, 32x32 tiles (1024 blocks)
// NOTE (r12 lesson): input cvt must stay a separate streaming pass — fusing
// it into the GEMM's A-staging replaces async DMA with sync loads and
// regressed qkv 41->100 us.
// ---------------------------------------------------------------------------
__global__ __launch_bounds__(256) void prep_kernel(
    const float* __restrict__ i0, const float* __restrict__ i1, const float* __restrict__ i2,
    unsigned short* __restrict__ o0, unsigned short* __restrict__ o1, unsigned short* __restrict__ o2,
    const float* __restrict__ w0, const float* __restrict__ w1,
    const float* __restrict__ w2, const float* __restrict__ w3,
    unsigned short* __restrict__ t0, unsigned short* __restrict__ t1,
    unsigned short* __restrict__ t2, unsigned short* __restrict__ t3,
    float* __restrict__ ct, float* __restrict__ st)
{
    const int z = blockIdx.z;
    const int bid = blockIdx.x, tid = threadIdx.x;

    if (z < 3) {
        const float* in = (z == 0) ? i0 : (z == 1) ? i1 : i2;
        unsigned short* out = (z == 0) ? o0 : (z == 1) ? o1 : o2;
        #pragma unroll
        for (int it = 0; it < 4; ++it) {
            size_t i = ((size_t)(it * 1024 + bid) * 256 + tid) * 4;
            float4 f = *(const float4*)(in + i);
            u16x4 r;
            r.x = f2bf(f.x); r.y = f2bf(f.y); r.z = f2bf(f.z); r.w = f2bf(f.w);
            *(u16x4*)(out + i) = r;
        }
    } else if (z == 3) {
        int idx = bid * 256 + tid;
        if (idx < LL * 32) {
            int l = idx >> 5, d = idx & 31;
            const float coef = -0.28782313662425583f;   // -ln(10000)/32
            float ang = (float)l * expf((float)d * coef);
            float s, c;
            sincosf(ang, &s, &c);
            ct[idx] = c;
            st[idx] = s;
        }
    } else {
        const int w = z - 4;
        const float* in = (w == 0) ? w0 : (w == 1) ? w1 : (w == 2) ? w2 : w3;
        unsigned short* out = (w == 0) ? t0 : (w == 1) ? t1 : (w == 2) ? t2 : t3;
        __shared__ float tile[32][33];
        int tx = tid & 31, ty = tid >> 5;   // 32 x 8
        int c0 = (bid & 31) * 32, r0 = (bid >> 5) * 32;
        #pragma unroll
        for (int j = 0; j < 32; j += 8)
            tile[ty + j][tx] = in[(size_t)(r0 + ty + j) * 1024 + c0 + tx];
        __syncthreads();
        #pragma unroll
        for (int j = 0; j < 32; j += 8)
            out[(size_t)(c0 + ty + j) * 1024 + r0 + tx] = f2bf(tile[tx][ty + j]);
    }
}

// ---------------------------------------------------------------------------
// bf16 MFMA GEMM core, 128x64 tile, single-buffered, BK=64, 24 KB LDS.
// LDS unpadded, XOR-swizzled (kb_phys = kb ^ (row&7)); 4 waves, wave's two
// n-tiles at cols wn*16 and wn*16+32 (one rope pair per lane).
// ---------------------------------------------------------------------------
__device__ __forceinline__ void gemm128x64_sb(
    const unsigned short* __restrict__ A, const unsigned short* __restrict__ Bt,
    unsigned short* As, unsigned short* Bs, int tM, int tN, f32x4 (&acc)[4][2])
{
    const int tid  = threadIdx.x;
    const int wave = tid >> 6, lane = tid & 63;
    const int g = lane >> 4, lm = lane & 15;
    const int wm = wave >> 1, wn = wave & 1;
    const int lr = lane >> 3, lk = lane & 7;
    const int kbl = lk ^ lr;                    // swizzled k-block for staging

    for (int kt = 0; kt < 16; ++kt) {
        const int k0 = kt * 64;
        if (kt) __syncthreads();
        #pragma unroll
        for (int it = 0; it < 4; ++it) {        // A: 128 rows
            int rbase = wave * 32 + it * 8;
            int r = rbase + lr;
            gl2lds16(A + (size_t)(tM + r) * 1024 + k0 + kbl * 8, As + rbase * 64);
        }
        #pragma unroll
        for (int it = 0; it < 2; ++it) {        // B: 64 rows
            int rbase = wave * 16 + it * 8;
            int r = rbase + lr;
            gl2lds16(Bt + (size_t)(tN + r) * 1024 + k0 + kbl * 8, Bs + rbase * 64);
        }
        __syncthreads();

        #pragma unroll
        for (int kk = 0; kk < 2; ++kk) {
            bf16x8 a[4], b[2];
            const int sw = ((kk * 4 + g) ^ (lm & 7)) * 8;
            #pragma unroll
            for (int mt = 0; mt < 4; ++mt)
                a[mt] = *(const bf16x8*)&As[(wm * 64 + mt * 16 + lm) * 64 + sw];
            #pragma unroll
            for (int nt = 0; nt < 2; ++nt)
                b[nt] = *(const bf16x8*)&Bs[(wn * 16 + nt * 32 + lm) * 64 + sw];
            #pragma unroll
            for (int mt = 0; mt < 4; ++mt)
                #pragma unroll
                for (int nt = 0; nt < 2; ++nt)
                    acc[mt][nt] = __builtin_amdgcn_mfma_f32_16x16x32_bf16(
                        a[mt], b[nt], acc[mt][nt], 0, 0, 0);
        }
    }
}

// ---------------------------------------------------------------------------
// QKV projections, fused over blockIdx.z (0=q rope+scale, 1=k rope, 2=v).
// grid (512, 1, 3) -> 6 blocks/CU. Q scale = 0.125*log2(e) (attn uses exp2).
// Each N-tile (64 cols) = exactly one head. z==2 writes V^T [bh][d][l] (b64).
// ---------------------------------------------------------------------------
__global__ __launch_bounds__(256) void gemm_qkv_kernel(
    const unsigned short* __restrict__ Aq, const unsigned short* __restrict__ Ak,
    const unsigned short* __restrict__ Av,
    const unsigned short* __restrict__ Wqt, const unsigned short* __restrict__ Wkt,
    const unsigned short* __restrict__ Wvt,
    const float* __restrict__ bq, const float* __restrict__ bk, const float* __restrict__ bv,
    const float* __restrict__ ct, const float* __restrict__ st,
    unsigned short* __restrict__ oq, unsigned short* __restrict__ ok,
    unsigned short* __restrict__ vt)
{
    __shared__ __align__(16) unsigned short As[128 * 64];
    __shared__ __align__(16) unsigned short Bs[64 * 64];

    const int z = blockIdx.z;
    const unsigned short* A  = (z == 0) ? Aq  : (z == 1) ? Ak  : Av;
    const unsigned short* Bt = (z == 0) ? Wqt : (z == 1) ? Wkt : Wvt;
    const float* bias        = (z == 0) ? bq  : (z == 1) ? bk  : bv;

    int tM, tN;
    tile_map64(blockIdx.x, tM, tN);
    f32x4 acc[4][2] = {};
    gemm128x64_sb(A, Bt, As, Bs, tM, tN, acc);

    const int wave = threadIdx.x >> 6, lane = threadIdx.x & 63;
    const int g = lane >> 4, lm = lane & 15;
    const int wm = wave >> 1, wn = wave & 1;

    const int h = tN >> 6;                      // this tile's head
    float bvv[2];
    #pragma unroll
    for (int nt = 0; nt < 2; ++nt) bvv[nt] = bias[tN + wn * 16 + nt * 32 + lm];

    if (z == 2) {                               // V: write V^T [bh][d][l], b64
        #pragma unroll
        for (int mt = 0; mt < 4; ++mt) {
            int row0 = tM + wm * 64 + mt * 16 + g * 4;   // 4 consecutive rows
            int b = row0 >> 10, l0 = row0 & 1023;
            #pragma unroll
            for (int nt = 0; nt < 2; ++nt) {
                int dloc = wn * 16 + nt * 32 + lm;
                u16x4 p4;
                #pragma unroll
                for (int r = 0; r < 4; ++r)
                    p4[r] = f2bf(acc[mt][nt][r] + bvv[nt]);
                *(u16x4*)(vt + (((size_t)(b * HH + h) * DH + dloc) << 10) + l0) = p4;
            }
        }
    } else {                                    // Q/K: rope from table
        unsigned short* out = (z == 0) ? oq : ok;
        const float sc = (z == 0) ? 0.125f * 1.4426950408889634f : 1.0f;
        const int dlo = wn * 16 + lm;           // in [0,32): rope pair (dlo, dlo+32)
        #pragma unroll
        for (int mt = 0; mt < 4; ++mt)
            #pragma unroll
            for (int r = 0; r < 4; ++r) {
                int row = tM + wm * 64 + mt * 16 + g * 4 + r;
                int b = row >> 10, l = row & 1023;
                float c = ct[l * 32 + dlo];
                float s = st[l * 32 + dlo];
                unsigned short* orow = out + ((size_t)(b * HH + h) * LL + l) * DH;
                float t1 = acc[mt][0][r] + bvv[0];
                float t2 = acc[mt][1][r] + bvv[1];
                orow[dlo]      = f2bf((t1 * c - t2 * s) * sc);
                orow[dlo + 32] = f2bf((t1 * s + t2 * c) * sc);
            }
    }
}

// ---------------------------------------------------------------------------
// Output projection: f32 C = ctx(bf16).Wot^T + bo. grid (512) -> 2 blocks/CU.
// ---------------------------------------------------------------------------
__global__ __launch_bounds__(256) void gemm_out_kernel(
    const unsigned short* __restrict__ A, const unsigned short* __restrict__ Bt,
    const float* __restrict__ bias, float* __restrict__ C)
{
    __shared__ __align__(16) unsigned short As[128 * 64];
    __shared__ __align__(16) unsigned short Bs[64 * 64];

    int tM, tN;
    tile_map64(blockIdx.x, tM, tN);
    f32x4 acc[4][2] = {};
    gemm128x64_sb(A, Bt, As, Bs, tM, tN, acc);

    const int wave = threadIdx.x >> 6, lane = threadIdx.x & 63;
    const int g = lane >> 4, lm = lane & 15;
    const int wm = wave >> 1, wn = wave & 1;

    float bvv[2];
    #pragma unroll
    for (int nt = 0; nt < 2; ++nt) bvv[nt] = bias[tN + wn * 16 + nt * 32 + lm];
    #pragma unroll
    for (int mt = 0; mt < 4; ++mt)
        #pragma unroll
        for (int r = 0; r < 4; ++r) {
            int row = tM + wm * 64 + mt * 16 + g * 4 + r;
            float* crow = C + (size_t)row * DM + tN;
            #pragma unroll
            for (int nt = 0; nt < 2; ++nt)
                crow[wn * 16 + nt * 32 + lm] = acc[mt][nt][r] + bvv[nt];
        }
}

// ---------------------------------------------------------------------------
// Flash-style bf16 MFMA attention, S^T form, 512-thread blocks (8 waves).
// Wave pairs: pair = wave>>1 owns q-strip rows pair*16..+15; half = wave&1
// splits the 64 j-columns (QK^T) and 64 d-outputs (PV). 4 blocks/CU x 8
// waves = 32 waves/CU. P pair-shared (disjoint j-halves), barrier before PV.
// 1-D grid, bh = n&63 so each head's blocks share an XCD (L2 locality).
// ---------------------------------------------------------------------------
#define PSTR 72

__global__ __launch_bounds__(512) void attn_mfma_kernel(
    const unsigned short* __restrict__ q, const unsigned short* __restrict__ k,
    const unsigned short* __restrict__ vt, unsigned short* __restrict__ ctx)
{
    __shared__ __align__(16) unsigned short Ks[64 * 64];
    __shared__ __align__(16) unsigned short Vs[64 * 64];
    __shared__ __align__(16) unsigned short Pb[4][16 * PSTR];
    __shared__ float Sm[4][2][16];

    const int tid  = threadIdx.x;
    const int wave = tid >> 6, lane = tid & 63;
    const int pair = wave >> 1, half = wave & 1;
    const int g = lane >> 4, lm = lane & 15;
    const int lr = lane >> 3, lk = lane & 7;
    const int kbl = lk ^ lr;
    const int n = blockIdx.x;
    const int bh = n & 63;              // XCD-swizzle: bh%8 == n%8 == XCD
    const int qbase = (n >> 6) * 64;

    const unsigned short* qg  = q  + (size_t)(bh * LL + qbase) * DH;
    const unsigned short* kg  = k  + (size_t)bh * LL * DH;
    const unsigned short* vtg = vt + (size_t)bh * DH * LL;   // [64 d][1024 l]

    bf16x8 aq[2];
    {
        const unsigned short* qrow = qg + (pair * 16 + lm) * DH;
        aq[0] = *(const bf16x8*)(qrow + g * 8);
        aq[1] = *(const bf16x8*)(qrow + 32 + g * 8);
    }

    f32x4 acc[2] = {};
    float lsum = 0.f;       // partial row-sum for m=lm over this wave's j-half

    for (int kt = 0; kt < 16; ++kt) {
        if (kt) __syncthreads();
        {   // 8 waves stage 64 K rows + 64 V^T rows in one call each
            int r = wave * 8 + lr;
            gl2lds16(kg  + (size_t)(kt * 64 + r) * DH + kbl * 8, Ks + wave * 8 * 64);
            gl2lds16(vtg + (size_t)r * LL + kt * 64 + kbl * 8,  Vs + wave * 8 * 64);
        }
        __syncthreads();

        // S^T = K . Q^T on this wave's j-half (t-tiles half*2, half*2+1)
        f32x4 s[2] = {};
        #pragma unroll
        for (int kk = 0; kk < 2; ++kk) {
            const int sw = ((kk * 4 + g) ^ (lm & 7)) * 8;
            #pragma unroll
            for (int t = 0; t < 2; ++t) {
                bf16x8 ak = *(const bf16x8*)&Ks[(half * 32 + t * 16 + lm) * 64 + sw];
                s[t] = __builtin_amdgcn_mfma_f32_16x16x32_bf16(ak, aq[kk], s[t], 0, 0, 0);
            }
        }

        // P = exp2(s); truncation-pack via v_perm; partial row sum
        #pragma unroll
        for (int t = 0; t < 2; ++t) {
            float p0 = exp2f(s[t][0]), p1 = exp2f(s[t][1]);
            float p2 = exp2f(s[t][2]), p3 = exp2f(s[t][3]);
            lsum += (p0 + p1) + (p2 + p3);
            u32x2 pk;
            pk[0] = __builtin_amdgcn_perm(fbits(p1), fbits(p0), 0x07060302u);
            pk[1] = __builtin_amdgcn_perm(fbits(p3), fbits(p2), 0x07060302u);
            *(u32x2*)&Pb[pair][lm * PSTR + half * 32 + t * 16 + g * 4] = pk;
        }
        __syncthreads();    // both j-halves of P visible across the pair

        // O += P V on this wave's d-half (dt-tiles half*2, half*2+1)
        #pragma unroll
        for (int kk = 0; kk < 2; ++kk) {
            const int sw = ((kk * 4 + g) ^ (lm & 7)) * 8;
            bf16x8 ap = *(const bf16x8*)&Pb[pair][lm * PSTR + kk * 32 + g * 8];
            #pragma unroll
            for (int dt = 0; dt < 2; ++dt) {
                bf16x8 bv = *(const bf16x8*)&Vs[(half * 32 + dt * 16 + lm) * 64 + sw];
                acc[dt] = __builtin_amdgcn_mfma_f32_16x16x32_bf16(ap, bv, acc[dt], 0, 0, 0);
            }
        }
    }

    // Row sums: reduce over g within wave, then combine halves via LDS
    float ts = lsum;
    ts += __shfl_xor(ts, 16, 64);
    ts += __shfl_xor(ts, 32, 64);
    if (lane < 16) Sm[pair][half][lane] = ts;
    __syncthreads();

    // Epilogue: lane's C rows are m = g*4+r; d = half*32 + dt*16 + lm
    int b = bh >> 4, h = bh & 15;
    #pragma unroll
    for (int r = 0; r < 4; ++r) {
        int m = g * 4 + r;
        float inv = 1.f / (Sm[pair][0][m] + Sm[pair][1][m]);
        int qrow = qbase + pair * 16 + m;
        unsigned short* orow = ctx + (size_t)(b * LL + qrow) * DM + h * DH;
        #pragma unroll
        for (int dt = 0; dt < 2; ++dt)
            orow[half * 32 + dt * 16 + lm] = f2bf(acc[dt][r] * inv);
    }
}

// ---------------------------------------------------------------------------
extern "C" void kernel_launch(void* const* d_in, const int* in_sizes, int n_in,
                              void* d_out, int out_size, void* d_ws, size_t ws_size,
                              hipStream_t stream) {
    const float* queries = (const float*)d_in[0];
    const float* keys    = (const float*)d_in[1];
    const float* values  = (const float*)d_in[2];
    const float* Wq = (const float*)d_in[3];
    const float* bq = (const float*)d_in[4];
    const float* Wk = (const float*)d_in[5];
    const float* bk = (const float*)d_in[6];
    const float* Wv = (const float*)d_in[7];
    const float* bv = (const float*)d_in[8];
    const float* Wo = (const float*)d_in[9];
    const float* bo = (const float*)d_in[10];
    float* out = (float*)d_out;

    // Workspace (bf16 elements), 64 MB total. Rope tables (256 KB f32) live at
    // the head of the ctx region: consumed by gemm_qkv BEFORE attn writes ctx.
    unsigned short* qb   = (unsigned short*)d_ws;
    unsigned short* kb_  = qb  + (size_t)MM * DM;
    unsigned short* vb_  = kb_ + (size_t)MM * DM;
    unsigned short* Wqt  = vb_ + (size_t)MM * DM;
    unsigned short* Wkt  = Wqt + (size_t)DM * DM;
    unsigned short* Wvt  = Wkt + (size_t)DM * DM;
    unsigned short* Wot  = Wvt + (size_t)DM * DM;
    unsigned short* q_ws = Wot + (size_t)DM * DM;
    unsigned short* k_ws = q_ws + (size_t)MM * DM;
    unsigned short* vt   = k_ws + (size_t)MM * DM;
    unsigned short* ctx  = vt   + (size_t)MM * DM;
    float* rope_cos = (float*)ctx;                 // 32K floats
    float* rope_sin = rope_cos + LL * 32;          // 32K floats

    prep_kernel<<<dim3(1024, 1, 8), 256, 0, stream>>>(
        queries, keys, values, qb, kb_, vb_,
        Wq, Wk, Wv, Wo, Wqt, Wkt, Wvt, Wot, rope_cos, rope_sin);
    gemm_qkv_kernel<<<dim3(512, 1, 3), 256, 0, stream>>>(
        qb, kb_, vb_, Wqt, Wkt, Wvt, bq, bk, bv, rope_cos, rope_sin,
        q_ws, k_ws, vt);
    attn_mfma_kernel<<<dim3(LL / 64 * BB * HH), 512, 0, stream>>>(
        q_ws, k_ws, vt, ctx);
    gemm_out_kernel<<<dim3(512), 256, 0, stream>>>(
        ctx, Wot, bo, out);
}